// Round 9
// baseline (109.335 us; speedup 1.0000x reference)
//
#include <hip/hip_runtime.h>

#define N_TOT 8192
#define NS 4096
#define D 256
#define NIP 32                // 256-row panels
#define NJP 64                // 128-col panels
#define NTILE 1056            // sum_{I<32} (64-2I)
#define HALF_B 32

typedef float f32x16 __attribute__((ext_vector_type(16)));
typedef float f32x2 __attribute__((ext_vector_type(2)));
typedef short bf16x8 __attribute__((ext_vector_type(8)));

__device__ __forceinline__ void gload16(const void* g, void* l) {
  __builtin_amdgcn_global_load_lds(
      (const __attribute__((address_space(1))) unsigned int*)g,
      (__attribute__((address_space(3))) unsigned int*)l,
      16, 0, 0);
}

// fp32 -> bf16 bits, round-to-nearest-even
__device__ __forceinline__ unsigned short f2bf(float f) {
  unsigned int u = __builtin_bit_cast(unsigned int, f);
  u += 0x7FFFu + ((u >> 16) & 1u);
  return (unsigned short)(u >> 16);
}

// ---- K1: one pass: bf16 convert + row sq-norms + per-block partials (r8) ----
__global__ void k_prep(const float* __restrict__ src, const float* __restrict__ tgt,
                       unsigned short* __restrict__ Xb, float* __restrict__ sqv,
                       float* __restrict__ pm, float* __restrict__ wsqp) {
  __shared__ float colacc[256];
  __shared__ float wred[4];
  int t = threadIdx.x, l = t & 63, w = t >> 6;
  colacc[t] = 0.f;
  __syncthreads();
  int base = blockIdx.x * 32;
  float c0 = 0.f, c1 = 0.f, c2 = 0.f, c3 = 0.f;
  float wsq = 0.f;
  #pragma unroll
  for (int r = 0; r < 8; ++r) {
    int row = base + w * 8 + r;
    const float* p = (row < NS) ? (src + (size_t)row * D) : (tgt + (size_t)(row - NS) * D);
    float4 v = ((const float4*)p)[l];
    ushort4 bv;
    bv.x = f2bf(v.x); bv.y = f2bf(v.y); bv.z = f2bf(v.z); bv.w = f2bf(v.w);
    ((ushort4*)(Xb + (size_t)row * D))[l] = bv;
    c0 += v.x; c1 += v.y; c2 += v.z; c3 += v.w;
    float s = fmaf(v.x, v.x, fmaf(v.y, v.y, fmaf(v.z, v.z, v.w * v.w)));
    for (int o = 32; o > 0; o >>= 1) s += __shfl_down(s, o, 64);
    if (l == 0) { sqv[row] = s; wsq += s; }
  }
  atomicAdd(&colacc[4 * l + 0], c0);
  atomicAdd(&colacc[4 * l + 1], c1);
  atomicAdd(&colacc[4 * l + 2], c2);
  atomicAdd(&colacc[4 * l + 3], c3);
  if (l == 0) wred[w] = wsq;
  __syncthreads();
  pm[blockIdx.x * 256 + t] = colacc[t];
  if (t == 0) wsqp[blockIdx.x] = (wred[0] + wred[1]) + (wred[2] + wred[3]);
}

// ---- K2: reduce partials, finalize bandwidth in fp64 (1 block) ----
__global__ void k_bw(const float* __restrict__ pm, const float* __restrict__ wsqp,
                     float* __restrict__ coef) {
  __shared__ double red[256];
  int t = threadIdx.x;
  float cs = 0.f;
  for (int b = 0; b < 256; ++b) cs += pm[b * 256 + t];
  red[t] = (double)cs * (double)cs;
  __syncthreads();
  for (int s = 128; s > 0; s >>= 1) {
    if (t < s) red[t] += red[t + s];
    __syncthreads();
  }
  double msq = red[0];
  __syncthreads();
  red[t] = (double)wsqp[t];
  __syncthreads();
  for (int s = 128; s > 0; s >>= 1) {
    if (t < s) red[t] += red[t + s];
    __syncthreads();
  }
  if (t == 0) {
    double Sv = red[0];
    double n = (double)N_TOT;
    double sumL2 = 2.0 * n * Sv - 2.0 * msq;
    double bw = sumL2 / (n * n - n) / 4.0;        // / KERNEL_MUL**(KERNEL_NUM//2)
    double c4 = 1.0 / (bw * 16.0 + 1e-6);         // widest kernel (k=4)
    coef[0] = (float)(c4 * 1.4426950408889634);   // * log2(e) for exp2
  }
}

// ---- K3: 256x128 tiles (J >= 2I), 512 threads, single-buffer BK=64 staging ----
// L2 traffic: 6 B/output vs 8 for 128x128 -> 203 MB total (was 532).
__global__ __launch_bounds__(512, 4) void k_main(
    const unsigned short* __restrict__ Xb, const float* __restrict__ sqv,
    const float* __restrict__ coef, float* __restrict__ bpart) {
  // decode b -> (I, J): offset(I) = I*(65-I), count 64-2I, J = 2I + rem
  int b = blockIdx.x;
  int I = (int)((65.f - sqrtf(65.f * 65.f - 4.f * (float)b)) * 0.5f);
  if (I < 0) I = 0;
  if (I > NIP - 1) I = NIP - 1;
  while (I * (65 - I) > b) --I;
  while ((I + 1) * (65 - (I + 1)) <= b) ++I;
  int J = 2 * I + (b - I * (65 - I));

  __shared__ unsigned short ldsA[256 * 64];   // 32 KB: A rows 0..255
  __shared__ unsigned short ldsB[128 * 64];   // 16 KB: B rows 0..127
  __shared__ float sqA[256], sqB[128];
  __shared__ float redw[8];

  int t = threadIdx.x, l = t & 63, w = t >> 6;       // w = 0..7
  int lr = l & 31, half = l >> 5;

  float A4 = coef[0];
  if (t < 256)      sqA[t] = sqv[I * 256 + t];
  else if (t < 384) sqB[t - 256] = sqv[J * 128 + (t - 256)];

  const unsigned short* arow = Xb + (size_t)I * 256 * D;
  const unsigned short* brow = Xb + (size_t)J * 128 * D;

  f32x16 acc[4] = {};    // wave owns rows [32w,32w+32) x cols [32cb,32cb+32)

  for (int ko = 0; ko < 4; ++ko) {
    if (ko) __syncthreads();
    int kOff = ko * 64;
    #pragma unroll
    for (int p = 0; p < 4; ++p) {      // A: 2048 16B segs
      int seg = p * 512 + t;
      int row = seg >> 3;
      int kb = (seg & 7) ^ (row & 7) ^ ((row >> 3) & 7);
      gload16(arow + row * D + kOff + kb * 8, &ldsA[(p * 512 + w * 64) * 8]);
    }
    #pragma unroll
    for (int p = 0; p < 2; ++p) {      // B: 1024 16B segs
      int seg = p * 512 + t;
      int row = seg >> 3;
      int kb = (seg & 7) ^ (row & 7) ^ ((row >> 3) & 7);
      gload16(brow + row * D + kOff + kb * 8, &ldsB[(p * 512 + w * 64) * 8]);
    }
    __syncthreads();
    #pragma unroll
    for (int ks = 0; ks < 4; ++ks) {
      int c = 2 * ks + half;                  // logical 16B chunk
      int rowA = 32 * w + lr;
      int physA = c ^ (rowA & 7) ^ ((rowA >> 3) & 7);
      bf16x8 aF = *(const bf16x8*)&ldsA[rowA * 64 + physA * 8];
      #pragma unroll
      for (int cb = 0; cb < 4; ++cb) {
        int rowB = 32 * cb + lr;
        int physB = c ^ (rowB & 7) ^ ((rowB >> 3) & 7);
        bf16x8 bF = *(const bf16x8*)&ldsB[rowB * 64 + physB * 8];
        acc[cb] = __builtin_amdgcn_mfma_f32_32x32x16_bf16(aF, bF, acc[cb], 0, 0, 0);
      }
    }
  }

  // Packed epilogue (exp-squaring). C/D: col=lane&31, row=(r&3)+8*(r>>2)+4*half
  // straddle tiles (J==2I or 2I+1): keep only gj>gi (uniform weight 2 outside)
  float c2A4 = 2.f * A4, nA4 = -A4;
  f32x2 lsum2 = {0.f, 0.f};
  bool straddle = ((J >> 1) == I);
  int dj = 128 * (J - 2 * I);          // 0 or 128 when straddle
  #pragma unroll
  for (int cb = 0; cb < 4; ++cb) {
    int jj = 32 * cb + lr;
    float bjv = nA4 * sqB[jj];
    #pragma unroll
    for (int r = 0; r < 16; r += 2) {
      int ii = 32 * w + (r & 3) + 8 * (r >> 2) + 4 * half;
      f32x2 dot2 = {acc[cb][r], acc[cb][r + 1]};
      f32x2 sq2 = {sqA[ii], sqA[ii + 1]};
      f32x2 tt = c2A4 * dot2 + (nA4 * sq2 + bjv);
      f32x2 e;
      e.x = __builtin_amdgcn_exp2f(tt.x);
      e.y = __builtin_amdgcn_exp2f(tt.y);
      f32x2 e2 = e * e, e4 = e2 * e2, e8 = e4 * e4, e16 = e8 * e8;
      f32x2 kern = ((e + e2) + (e4 + e8)) + e16;
      if (straddle) {                  // block-uniform branch
        if (jj + dj <= ii) kern.x = 0.f;
        if (jj + dj <= ii + 1) kern.y = 0.f;
      }
      lsum2 += kern;
    }
  }
  float lsum = lsum2.x + lsum2.y;
  for (int o = 32; o > 0; o >>= 1) lsum += __shfl_down(lsum, o, 64);
  if (l == 0) redw[w] = lsum;
  __syncthreads();
  if (t == 0) {
    float tot = ((redw[0] + redw[1]) + (redw[2] + redw[3])) +
                ((redw[4] + redw[5]) + (redw[6] + redw[7]));
    float sgn = ((I < 16) == (J < 32)) ? 1.f : -1.f;   // s_i * s_j (block-uniform)
    bpart[b] = tot * 2.f * sgn;                        // weight 2 everywhere
  }
}

// ---- K4: final fp64 reduction + analytic diagonal + mean ----
__global__ void k_final(const float* __restrict__ bpart, float* __restrict__ out) {
  __shared__ double red[256];
  int t = threadIdx.x;
  double s = 0.0;
  for (int k = 0; k < 5; ++k) {
    int idx = k * 256 + t;
    if (idx < NTILE) s += (double)bpart[idx];
  }
  red[t] = s;
  __syncthreads();
  for (int st = 128; st > 0; st >>= 1) {
    if (t < st) red[t] += red[t + st];
    __syncthreads();
  }
  if (t == 0) {
    double total = red[0] + 5.0 * (double)N_TOT;  // diagonal: K_ii = 5, sign +1
    out[0] = (float)(total / ((double)NS * (double)NS));
  }
}

extern "C" void kernel_launch(void* const* d_in, const int* in_sizes, int n_in,
                              void* d_out, int out_size, void* d_ws, size_t ws_size,
                              hipStream_t stream) {
  const float* src = (const float*)d_in[0];
  const float* tgt = (const float*)d_in[1];
  float* out = (float*)d_out;
  char* ws = (char*)d_ws;
  unsigned short* Xb = (unsigned short*)ws;                     // 4 MB bf16 row-major
  float* sqv  = (float*)(ws + (4u << 20));                      // 32 KB row sq-norms
  float* pm   = (float*)(ws + (4u << 20) + (32u << 10));        // 256 KB col partials
  float* wsqp = (float*)(ws + (4u << 20) + (288u << 10));       // 1 KB sq partials
  float* coef = (float*)(ws + (4u << 20) + (289u << 10));       // 4 B
  float* bpart = (float*)(ws + (4u << 20) + (290u << 10));      // 4.2 KB tile partials

  hipLaunchKernelGGL(k_prep, dim3(256), dim3(256), 0, stream, src, tgt, Xb, sqv, pm, wsqp);
  hipLaunchKernelGGL(k_bw, dim3(1), dim3(256), 0, stream, pm, wsqp, coef);
  hipLaunchKernelGGL(k_main, dim3(NTILE), dim3(512), 0, stream, Xb, sqv, coef, bpart);
  hipLaunchKernelGGL(k_final, dim3(1), dim3(256), 0, stream, bpart, out);
}

// Round 10
// 100.256 us; speedup vs baseline: 1.0906x; 1.0906x over previous
//
#include <hip/hip_runtime.h>

#define N_TOT 8192
#define NS 4096
#define D 256                 // elements per row; fp8 => also bytes per row
#define NB 64                 // 8192/128 tiles per dim
#define NTRI (NB*(NB+1)/2)    // 2080 upper-triangle tiles
#define HALF_B 32

typedef float f32x16 __attribute__((ext_vector_type(16)));
typedef float f32x2 __attribute__((ext_vector_type(2)));

__device__ __forceinline__ void gload16(const void* g, void* l) {
  __builtin_amdgcn_global_load_lds(
      (const __attribute__((address_space(1))) unsigned int*)g,
      (__attribute__((address_space(3))) unsigned int*)l,
      16, 0, 0);
}

// ---- K1: one pass: fp8 e4m3 convert + row sq-norms + per-block partials ----
__global__ void k_prep(const float* __restrict__ src, const float* __restrict__ tgt,
                       unsigned char* __restrict__ Xb, float* __restrict__ sqv,
                       float* __restrict__ pm, float* __restrict__ wsqp) {
  __shared__ float colacc[256];
  __shared__ float wred[4];
  int t = threadIdx.x, l = t & 63, w = t >> 6;
  colacc[t] = 0.f;
  __syncthreads();
  int base = blockIdx.x * 32;
  float c0 = 0.f, c1 = 0.f, c2 = 0.f, c3 = 0.f;
  float wsq = 0.f;
  #pragma unroll
  for (int r = 0; r < 8; ++r) {
    int row = base + w * 8 + r;
    const float* p = (row < NS) ? (src + (size_t)row * D) : (tgt + (size_t)(row - NS) * D);
    float4 v = ((const float4*)p)[l];
    int pk = __builtin_amdgcn_cvt_pk_fp8_f32(v.x, v.y, 0, false);   // bytes 0,1
    pk = __builtin_amdgcn_cvt_pk_fp8_f32(v.z, v.w, pk, true);       // bytes 2,3
    ((int*)(Xb + (size_t)row * D))[l] = pk;                         // 4 B/lane coalesced
    c0 += v.x; c1 += v.y; c2 += v.z; c3 += v.w;
    float s = fmaf(v.x, v.x, fmaf(v.y, v.y, fmaf(v.z, v.z, v.w * v.w)));
    for (int o = 32; o > 0; o >>= 1) s += __shfl_down(s, o, 64);
    if (l == 0) { sqv[row] = s; wsq += s; }
  }
  atomicAdd(&colacc[4 * l + 0], c0);
  atomicAdd(&colacc[4 * l + 1], c1);
  atomicAdd(&colacc[4 * l + 2], c2);
  atomicAdd(&colacc[4 * l + 3], c3);
  if (l == 0) wred[w] = wsq;
  __syncthreads();
  pm[blockIdx.x * 256 + t] = colacc[t];
  if (t == 0) wsqp[blockIdx.x] = (wred[0] + wred[1]) + (wred[2] + wred[3]);
}

// ---- K2: reduce partials, finalize bandwidth in fp64 (1 block) ----
__global__ void k_bw(const float* __restrict__ pm, const float* __restrict__ wsqp,
                     float* __restrict__ coef) {
  __shared__ double red[256];
  int t = threadIdx.x;
  float cs = 0.f;
  for (int b = 0; b < 256; ++b) cs += pm[b * 256 + t];
  red[t] = (double)cs * (double)cs;
  __syncthreads();
  for (int s = 128; s > 0; s >>= 1) {
    if (t < s) red[t] += red[t + s];
    __syncthreads();
  }
  double msq = red[0];
  __syncthreads();
  red[t] = (double)wsqp[t];
  __syncthreads();
  for (int s = 128; s > 0; s >>= 1) {
    if (t < s) red[t] += red[t + s];
    __syncthreads();
  }
  if (t == 0) {
    double Sv = red[0];
    double n = (double)N_TOT;
    double sumL2 = 2.0 * n * Sv - 2.0 * msq;
    double bw = sumL2 / (n * n - n) / 4.0;        // / KERNEL_MUL**(KERNEL_NUM//2)
    double c4 = 1.0 / (bw * 16.0 + 1e-6);         // widest kernel (k=4)
    coef[0] = (float)(c4 * 1.4426950408889634);   // * log2(e) for exp2
  }
}

// ---- K3: 128x128 upper-tri tiles, fp8 e4m3 MFMA, r5 single-buffer structure ----
// Per stage: 64 B/row (4x16B chunks). Swizzle phys = chunk ^ (row&3) ^ ((row>>2)&3)
// (bijective per row; read-side worst case 2-way = free).
__global__ __launch_bounds__(256) void k_main(
    const unsigned char* __restrict__ Xb, const float* __restrict__ sqv,
    const float* __restrict__ coef, float* __restrict__ bpart) {
  // triangular decode: block b -> (bi, bj), bi <= bj
  int b = blockIdx.x;
  int bi = (int)((2.f * NB + 1.f - sqrtf((float)((2 * NB + 1) * (2 * NB + 1) - 8 * b))) * 0.5f);
  if (bi < 0) bi = 0;
  if (bi > NB - 1) bi = NB - 1;
  while ((bi + 1) * (2 * NB - bi) / 2 <= b) ++bi;
  while (bi * (2 * NB - bi + 1) / 2 > b) --bi;
  int bj = bi + (b - bi * (2 * NB - bi + 1) / 2);

  __shared__ unsigned char ldsA[128 * 64];   // 8 KB  [row][64B stage-slice]
  __shared__ unsigned char ldsB[128 * 64];   // 8 KB
  __shared__ float sqA[128], sqB[128];
  __shared__ float redw[4];

  int t = threadIdx.x, l = t & 63, w = t >> 6;
  int lr = l & 31, half = l >> 5;
  int waveRow = w >> 1, waveCol = w & 1;

  if (t < 128) sqA[t] = sqv[bi * 128 + t];
  else         sqB[t - 128] = sqv[bj * 128 + (t - 128)];
  float A4 = coef[0];

  const unsigned char* arow = Xb + (size_t)bi * 128 * D;
  const unsigned char* brow = Xb + (size_t)bj * 128 * D;

  f32x16 acc[2][2] = {};

  for (int ko = 0; ko < 4; ++ko) {
    if (ko) __syncthreads();
    int kOff = ko * 64;                     // byte offset in row
    #pragma unroll
    for (int p = 0; p < 2; ++p) {           // 512 16B segs per matrix
      int seg = p * 256 + t;
      int row = seg >> 2;
      int kb = (seg & 3) ^ (row & 3) ^ ((row >> 2) & 3);
      int goff = row * D + kOff + kb * 16;
      gload16(arow + goff, &ldsA[(p * 256 + w * 64) * 16]);
      gload16(brow + goff, &ldsB[(p * 256 + w * 64) * 16]);
    }
    __syncthreads();
    #pragma unroll
    for (int ks = 0; ks < 4; ++ks) {        // K=16 per MFMA
      unsigned long long aF[2], bF[2];
      #pragma unroll
      for (int rb = 0; rb < 2; ++rb) {
        int rowA = waveRow * 64 + rb * 32 + lr;
        int physA = ks ^ (rowA & 3) ^ ((rowA >> 2) & 3);
        aF[rb] = *(const unsigned long long*)&ldsA[rowA * 64 + physA * 16 + 8 * half];
        int rowB = waveCol * 64 + rb * 32 + lr;
        int physB = ks ^ (rowB & 3) ^ ((rowB >> 2) & 3);
        bF[rb] = *(const unsigned long long*)&ldsB[rowB * 64 + physB * 16 + 8 * half];
      }
      #pragma unroll
      for (int rb = 0; rb < 2; ++rb)
        #pragma unroll
        for (int cb = 0; cb < 2; ++cb)
          acc[rb][cb] = __builtin_amdgcn_mfma_f32_32x32x16_fp8_fp8(
              (long)aF[rb], (long)bF[cb], acc[rb][cb], 0, 0, 0);
    }
  }

  // Packed epilogue: tt = 2A4*dot - A4*sqi - A4*sqj ; e = exp2(tt)
  // sum5 = e+e^2+e^4+e^8+e^16 (exp-squaring; bw_k = bw*2^k exactly)
  // C/D layout (shape-determined, dtype-independent): col=lane&31,
  // row=(r&3)+8*(r>>2)+4*(lane>>5)
  float c2A4 = 2.f * A4, nA4 = -A4;
  f32x2 lsum2 = {0.f, 0.f};
  bool diag = (bi == bj);
  #pragma unroll
  for (int cb = 0; cb < 2; ++cb) {
    int jj = waveCol * 64 + cb * 32 + lr;
    float bjv = nA4 * sqB[jj];
    #pragma unroll
    for (int rb = 0; rb < 2; ++rb) {
      #pragma unroll
      for (int r = 0; r < 16; r += 2) {
        int ii = waveRow * 64 + rb * 32 + (r & 3) + 8 * (r >> 2) + 4 * half;
        f32x2 dot2 = {acc[rb][cb][r], acc[rb][cb][r + 1]};
        f32x2 sq2 = {sqA[ii], sqA[ii + 1]};
        f32x2 tt = c2A4 * dot2 + (nA4 * sq2 + bjv);
        f32x2 e;
        e.x = __builtin_amdgcn_exp2f(tt.x);
        e.y = __builtin_amdgcn_exp2f(tt.y);
        f32x2 e2 = e * e, e4 = e2 * e2, e8 = e4 * e4, e16 = e8 * e8;
        f32x2 kern = ((e + e2) + (e4 + e8)) + e16;
        if (diag) {                          // block-uniform branch
          if (ii == jj) kern.x = 0.f;
          if (ii + 1 == jj) kern.y = 0.f;
        }
        lsum2 += kern;
      }
    }
  }
  float lsum = lsum2.x + lsum2.y;
  for (int o = 32; o > 0; o >>= 1) lsum += __shfl_down(lsum, o, 64);
  if (l == 0) redw[w] = lsum;
  __syncthreads();
  if (t == 0) {
    float tot = (redw[0] + redw[1]) + (redw[2] + redw[3]);
    float wgt = diag ? 1.f : 2.f;                               // symmetry weight
    float sgn = ((bi < HALF_B) == (bj < HALF_B)) ? 1.f : -1.f;  // s_i * s_j
    bpart[b] = tot * wgt * sgn;
  }
}

// ---- K4: final fp64 reduction + analytic diagonal + mean ----
__global__ void k_final(const float* __restrict__ bpart, float* __restrict__ out) {
  __shared__ double red[256];
  int t = threadIdx.x;
  double s = 0.0;
  for (int k = 0; k < 9; ++k) {
    int idx = k * 256 + t;
    if (idx < NTRI) s += (double)bpart[idx];
  }
  red[t] = s;
  __syncthreads();
  for (int st = 128; st > 0; st >>= 1) {
    if (t < st) red[t] += red[t + st];
    __syncthreads();
  }
  if (t == 0) {
    double total = red[0] + 5.0 * (double)N_TOT;  // diagonal: K_ii = 5, sign +1
    out[0] = (float)(total / ((double)NS * (double)NS));
  }
}

extern "C" void kernel_launch(void* const* d_in, const int* in_sizes, int n_in,
                              void* d_out, int out_size, void* d_ws, size_t ws_size,
                              hipStream_t stream) {
  const float* src = (const float*)d_in[0];
  const float* tgt = (const float*)d_in[1];
  float* out = (float*)d_out;
  char* ws = (char*)d_ws;
  unsigned char* Xb = (unsigned char*)ws;                       // 2 MB fp8 row-major
  float* sqv  = (float*)(ws + (4u << 20));                      // 32 KB row sq-norms
  float* pm   = (float*)(ws + (4u << 20) + (32u << 10));        // 256 KB col partials
  float* wsqp = (float*)(ws + (4u << 20) + (288u << 10));       // 1 KB sq partials
  float* coef = (float*)(ws + (4u << 20) + (289u << 10));       // 4 B
  float* bpart = (float*)(ws + (4u << 20) + (290u << 10));      // 8.3 KB tile partials

  hipLaunchKernelGGL(k_prep, dim3(256), dim3(256), 0, stream, src, tgt, Xb, sqv, pm, wsqp);
  hipLaunchKernelGGL(k_bw, dim3(1), dim3(256), 0, stream, pm, wsqp, coef);
  hipLaunchKernelGGL(k_main, dim3(NTRI), dim3(256), 0, stream, Xb, sqv, coef, bpart);
  hipLaunchKernelGGL(k_final, dim3(1), dim3(256), 0, stream, bpart, out);
}

// Round 11
// 98.562 us; speedup vs baseline: 1.1093x; 1.0172x over previous
//
#include <hip/hip_runtime.h>

#define N_TOT 8192
#define NS 4096
#define D 256                 // elements per row; fp8 => also bytes per row
#define NB 64                 // 8192/128 tiles per dim
#define NTRI (NB*(NB+1)/2)    // 2080 upper-triangle tiles
#define HALF_B 32

typedef float f32x16 __attribute__((ext_vector_type(16)));
typedef float f32x2 __attribute__((ext_vector_type(2)));
typedef int i32x4 __attribute__((ext_vector_type(4)));
typedef int i32x8 __attribute__((ext_vector_type(8)));

__device__ __forceinline__ void gload16(const void* g, void* l) {
  __builtin_amdgcn_global_load_lds(
      (const __attribute__((address_space(1))) unsigned int*)g,
      (__attribute__((address_space(3))) unsigned int*)l,
      16, 0, 0);
}

// ---- K1: one pass: fp8 e4m3 convert + row sq-norms + per-block partials ----
__global__ void k_prep(const float* __restrict__ src, const float* __restrict__ tgt,
                       unsigned char* __restrict__ Xb, float* __restrict__ sqv,
                       float* __restrict__ pm, float* __restrict__ wsqp) {
  __shared__ float colacc[256];
  __shared__ float wred[4];
  int t = threadIdx.x, l = t & 63, w = t >> 6;
  colacc[t] = 0.f;
  __syncthreads();
  int base = blockIdx.x * 32;
  float c0 = 0.f, c1 = 0.f, c2 = 0.f, c3 = 0.f;
  float wsq = 0.f;
  #pragma unroll
  for (int r = 0; r < 8; ++r) {
    int row = base + w * 8 + r;
    const float* p = (row < NS) ? (src + (size_t)row * D) : (tgt + (size_t)(row - NS) * D);
    float4 v = ((const float4*)p)[l];
    int pk = __builtin_amdgcn_cvt_pk_fp8_f32(v.x, v.y, 0, false);   // bytes 0,1
    pk = __builtin_amdgcn_cvt_pk_fp8_f32(v.z, v.w, pk, true);       // bytes 2,3
    ((int*)(Xb + (size_t)row * D))[l] = pk;                         // 4 B/lane coalesced
    c0 += v.x; c1 += v.y; c2 += v.z; c3 += v.w;
    float s = fmaf(v.x, v.x, fmaf(v.y, v.y, fmaf(v.z, v.z, v.w * v.w)));
    for (int o = 32; o > 0; o >>= 1) s += __shfl_down(s, o, 64);
    if (l == 0) { sqv[row] = s; wsq += s; }
  }
  atomicAdd(&colacc[4 * l + 0], c0);
  atomicAdd(&colacc[4 * l + 1], c1);
  atomicAdd(&colacc[4 * l + 2], c2);
  atomicAdd(&colacc[4 * l + 3], c3);
  if (l == 0) wred[w] = wsq;
  __syncthreads();
  pm[blockIdx.x * 256 + t] = colacc[t];
  if (t == 0) wsqp[blockIdx.x] = (wred[0] + wred[1]) + (wred[2] + wred[3]);
}

// ---- K2: reduce partials, finalize bandwidth in fp64 (1 block) ----
__global__ void k_bw(const float* __restrict__ pm, const float* __restrict__ wsqp,
                     float* __restrict__ coef) {
  __shared__ double red[256];
  int t = threadIdx.x;
  float cs = 0.f;
  for (int b = 0; b < 256; ++b) cs += pm[b * 256 + t];
  red[t] = (double)cs * (double)cs;
  __syncthreads();
  for (int s = 128; s > 0; s >>= 1) {
    if (t < s) red[t] += red[t + s];
    __syncthreads();
  }
  double msq = red[0];
  __syncthreads();
  red[t] = (double)wsqp[t];
  __syncthreads();
  for (int s = 128; s > 0; s >>= 1) {
    if (t < s) red[t] += red[t + s];
    __syncthreads();
  }
  if (t == 0) {
    double Sv = red[0];
    double n = (double)N_TOT;
    double sumL2 = 2.0 * n * Sv - 2.0 * msq;
    double bw = sumL2 / (n * n - n) / 4.0;        // / KERNEL_MUL**(KERNEL_NUM//2)
    double c4 = 1.0 / (bw * 16.0 + 1e-6);         // widest kernel (k=4)
    coef[0] = (float)(c4 * 1.4426950408889634);   // * log2(e) for exp2
  }
}

// ---- K3: 128x128 upper-tri tiles, MX-scaled fp8 32x32x64 MFMA (unit scales) ----
// One K=64 MFMA per (rb,cb) per stage: 4 MFMA + 8 ds_read_b128 per wave-stage
// (was 16 MFMA + 16 ds_read_b64). Scale byte 127 = e8m0 2^0 = exactly 1.0,
// so arithmetic is identical to the non-scaled fp8 path (r10, absmax 0).
__global__ __launch_bounds__(256) void k_main(
    const unsigned char* __restrict__ Xb, const float* __restrict__ sqv,
    const float* __restrict__ coef, float* __restrict__ bpart) {
  // triangular decode: block b -> (bi, bj), bi <= bj
  int b = blockIdx.x;
  int bi = (int)((2.f * NB + 1.f - sqrtf((float)((2 * NB + 1) * (2 * NB + 1) - 8 * b))) * 0.5f);
  if (bi < 0) bi = 0;
  if (bi > NB - 1) bi = NB - 1;
  while ((bi + 1) * (2 * NB - bi) / 2 <= b) ++bi;
  while (bi * (2 * NB - bi + 1) / 2 > b) --bi;
  int bj = bi + (b - bi * (2 * NB - bi + 1) / 2);

  __shared__ unsigned char ldsA[128 * 64];   // 8 KB  [row][64B stage-slice]
  __shared__ unsigned char ldsB[128 * 64];   // 8 KB
  __shared__ float sqA[128], sqB[128];
  __shared__ float redw[4];

  int t = threadIdx.x, l = t & 63, w = t >> 6;
  int lr = l & 31, half = l >> 5;
  int waveRow = w >> 1, waveCol = w & 1;

  if (t < 128) sqA[t] = sqv[bi * 128 + t];
  else         sqB[t - 128] = sqv[bj * 128 + (t - 128)];
  float A4 = coef[0];

  const unsigned char* arow = Xb + (size_t)bi * 128 * D;
  const unsigned char* brow = Xb + (size_t)bj * 128 * D;

  f32x16 acc[2][2] = {};
  int cLo = 2 * half, cHi = 2 * half + 1;   // logical 16B chunks for this lane's k-window

  for (int ko = 0; ko < 4; ++ko) {
    if (ko) __syncthreads();
    int kOff = ko * 64;                     // byte offset in row
    #pragma unroll
    for (int p = 0; p < 2; ++p) {           // 512 16B segs per matrix
      int seg = p * 256 + t;
      int row = seg >> 2;
      int kb = (seg & 3) ^ (row & 3) ^ ((row >> 2) & 3);
      int goff = row * D + kOff + kb * 16;
      gload16(arow + goff, &ldsA[(p * 256 + w * 64) * 16]);
      gload16(brow + goff, &ldsB[(p * 256 + w * 64) * 16]);
    }
    __syncthreads();
    // A fragments (32 B = lane's k-window [32*half, 32*half+32) of the stage)
    i32x8 aF[2];
    #pragma unroll
    for (int rb = 0; rb < 2; ++rb) {
      int rowA = waveRow * 64 + rb * 32 + lr;
      int sw = (rowA & 3) ^ ((rowA >> 2) & 3);
      i32x4 lo = *(const i32x4*)&ldsA[rowA * 64 + (cLo ^ sw) * 16];
      i32x4 hi = *(const i32x4*)&ldsA[rowA * 64 + (cHi ^ sw) * 16];
      aF[rb] = (i32x8){lo.x, lo.y, lo.z, lo.w, hi.x, hi.y, hi.z, hi.w};
    }
    #pragma unroll
    for (int cb = 0; cb < 2; ++cb) {
      int rowB = waveCol * 64 + cb * 32 + lr;
      int sw = (rowB & 3) ^ ((rowB >> 2) & 3);
      i32x4 lo = *(const i32x4*)&ldsB[rowB * 64 + (cLo ^ sw) * 16];
      i32x4 hi = *(const i32x4*)&ldsB[rowB * 64 + (cHi ^ sw) * 16];
      i32x8 bF = (i32x8){lo.x, lo.y, lo.z, lo.w, hi.x, hi.y, hi.z, hi.w};
      #pragma unroll
      for (int rb = 0; rb < 2; ++rb)
        acc[rb][cb] = __builtin_amdgcn_mfma_scale_f32_32x32x64_f8f6f4(
            aF[rb], bF, acc[rb][cb], 0, 0, 0, 127, 0, 127);
    }
  }

  // Packed epilogue: tt = 2A4*dot - A4*sqi - A4*sqj ; e = exp2(tt)
  // sum5 = e+e^2+e^4+e^8+e^16 (exp-squaring; bw_k = bw*2^k exactly)
  // C/D layout (shape-determined, dtype-independent): col=lane&31,
  // row=(r&3)+8*(r>>2)+4*(lane>>5)
  float c2A4 = 2.f * A4, nA4 = -A4;
  f32x2 lsum2 = {0.f, 0.f};
  bool diag = (bi == bj);
  #pragma unroll
  for (int cb = 0; cb < 2; ++cb) {
    int jj = waveCol * 64 + cb * 32 + lr;
    float bjv = nA4 * sqB[jj];
    #pragma unroll
    for (int rb = 0; rb < 2; ++rb) {
      #pragma unroll
      for (int r = 0; r < 16; r += 2) {
        int ii = waveRow * 64 + rb * 32 + (r & 3) + 8 * (r >> 2) + 4 * half;
        f32x2 dot2 = {acc[rb][cb][r], acc[rb][cb][r + 1]};
        f32x2 sq2 = {sqA[ii], sqA[ii + 1]};
        f32x2 tt = c2A4 * dot2 + (nA4 * sq2 + bjv);
        f32x2 e;
        e.x = __builtin_amdgcn_exp2f(tt.x);
        e.y = __builtin_amdgcn_exp2f(tt.y);
        f32x2 e2 = e * e, e4 = e2 * e2, e8 = e4 * e4, e16 = e8 * e8;
        f32x2 kern = ((e + e2) + (e4 + e8)) + e16;
        if (diag) {                          // block-uniform branch
          if (ii == jj) kern.x = 0.f;
          if (ii + 1 == jj) kern.y = 0.f;
        }
        lsum2 += kern;
      }
    }
  }
  float lsum = lsum2.x + lsum2.y;
  for (int o = 32; o > 0; o >>= 1) lsum += __shfl_down(lsum, o, 64);
  if (l == 0) redw[w] = lsum;
  __syncthreads();
  if (t == 0) {
    float tot = (redw[0] + redw[1]) + (redw[2] + redw[3]);
    float wgt = diag ? 1.f : 2.f;                               // symmetry weight
    float sgn = ((bi < HALF_B) == (bj < HALF_B)) ? 1.f : -1.f;  // s_i * s_j
    bpart[b] = tot * wgt * sgn;
  }
}

// ---- K4: final fp64 reduction + analytic diagonal + mean ----
__global__ void k_final(const float* __restrict__ bpart, float* __restrict__ out) {
  __shared__ double red[256];
  int t = threadIdx.x;
  double s = 0.0;
  for (int k = 0; k < 9; ++k) {
    int idx = k * 256 + t;
    if (idx < NTRI) s += (double)bpart[idx];
  }
  red[t] = s;
  __syncthreads();
  for (int st = 128; st > 0; st >>= 1) {
    if (t < st) red[t] += red[t + st];
    __syncthreads();
  }
  if (t == 0) {
    double total = red[0] + 5.0 * (double)N_TOT;  // diagonal: K_ii = 5, sign +1
    out[0] = (float)(total / ((double)NS * (double)NS));
  }
}

extern "C" void kernel_launch(void* const* d_in, const int* in_sizes, int n_in,
                              void* d_out, int out_size, void* d_ws, size_t ws_size,
                              hipStream_t stream) {
  const float* src = (const float*)d_in[0];
  const float* tgt = (const float*)d_in[1];
  float* out = (float*)d_out;
  char* ws = (char*)d_ws;
  unsigned char* Xb = (unsigned char*)ws;                       // 2 MB fp8 row-major
  float* sqv  = (float*)(ws + (4u << 20));                      // 32 KB row sq-norms
  float* pm   = (float*)(ws + (4u << 20) + (32u << 10));        // 256 KB col partials
  float* wsqp = (float*)(ws + (4u << 20) + (288u << 10));       // 1 KB sq partials
  float* coef = (float*)(ws + (4u << 20) + (289u << 10));       // 4 B
  float* bpart = (float*)(ws + (4u << 20) + (290u << 10));      // 8.3 KB tile partials

  hipLaunchKernelGGL(k_prep, dim3(256), dim3(256), 0, stream, src, tgt, Xb, sqv, pm, wsqp);
  hipLaunchKernelGGL(k_bw, dim3(1), dim3(256), 0, stream, pm, wsqp, coef);
  hipLaunchKernelGGL(k_main, dim3(NTRI), dim3(256), 0, stream, Xb, sqv, coef, bpart);
  hipLaunchKernelGGL(k_final, dim3(1), dim3(256), 0, stream, bpart, out);
}